// Round 4
// baseline (249.691 us; speedup 1.0000x reference)
//
#include <hip/hip_runtime.h>

// Problem constants (from reference)
constexpr int kB   = 16384;   // batch
constexpr int kNeg = 10;      // negatives per example
constexpr int kE   = 128;     // embedding dim
constexpr int kWavesPerBlock = 4;                 // 256 threads
constexpr int kExPerWave     = 2;                 // 32 lanes per example
constexpr int kBlocks = kB / (kWavesPerBlock * kExPerWave);   // 2048

// Module-scope completion counter: NOT in the (re-poisoned) workspace.
// Loaded as 0; the last-done block resets it to 0 before exiting, so every
// graph replay starts from 0. No grid sync, no spin — the last block to
// increment does the final reduction in fixed index order (deterministic).
__device__ int g_done = 0;

__device__ __forceinline__ float log_sigmoid(float x) {
    // numerically stable: min(x,0) - log1p(exp(-|x|))
    return fminf(x, 0.0f) - log1pf(expf(-fabsf(x)));
}

__device__ __forceinline__ float dot4(float4 a, float4 b) {
    return a.x * b.x + a.y * b.y + a.z * b.z + a.w * b.w;
}

// R0-proven gather body + fused last-block reduction (single dispatch).
__global__ __launch_bounds__(256, 4) void w2v_loss_fused(
    const int*   __restrict__ input_word,
    const int*   __restrict__ context_word,
    const int*   __restrict__ noise_words,
    const float* __restrict__ W_in,
    const float* __restrict__ W_ctx,
    float*       __restrict__ partials,
    float*       __restrict__ out)
{
    const int tid  = threadIdx.x;
    const int wave = tid >> 6;
    const int lane = tid & 63;
    const int half = lane >> 5;               // which example of the wave
    const int l32  = lane & 31;               // lane within 32-lane group

    const int b = (blockIdx.x * kWavesPerBlock + wave) * kExPerWave + half;

    // Load all indices first (independent scalar loads).
    const int iw = input_word[b];
    const int cw = context_word[b];
    int nw[kNeg];
    #pragma unroll
    for (int k = 0; k < kNeg; ++k)
        nw[k] = noise_words[b * kNeg + k];

    // Issue all 12 row gathers back-to-back (each 1 float4/lane, 512B/row).
    const float4 c = ((const float4*)(W_in  + (size_t)iw * kE))[l32];
    const float4 x = ((const float4*)(W_ctx + (size_t)cw * kE))[l32];
    float4 nv[kNeg];
    #pragma unroll
    for (int k = 0; k < kNeg; ++k)
        nv[k] = ((const float4*)(W_ctx + (size_t)nw[k] * kE))[l32];

    float pos = dot4(c, x);
    float negp[kNeg];
    #pragma unroll
    for (int k = 0; k < kNeg; ++k)
        negp[k] = dot4(c, nv[k]);

    // 5-step butterfly within each 32-lane half (xor masks < 32 stay in-half).
    #pragma unroll
    for (int off = 16; off > 0; off >>= 1) {
        pos += __shfl_xor(pos, off);
        #pragma unroll
        for (int k = 0; k < kNeg; ++k)
            negp[k] += __shfl_xor(negp[k], off);
    }
    // Every lane now holds all 11 full dot products for its example.

    // Distribute the 11 log_sigmoid evaluations across lanes 0..10 of the half.
    float v = pos;                          // lane 0: positive score
    #pragma unroll
    for (int k = 0; k < kNeg; ++k)
        v = (l32 == k + 1) ? -negp[k] : v;  // lanes 1..10: negated neg scores
    float s = (l32 < 1 + kNeg) ? log_sigmoid(v) : 0.0f;

    // Sum the 11 terms within the half (5 steps), then across halves (1 step).
    #pragma unroll
    for (int off = 16; off > 0; off >>= 1)
        s += __shfl_xor(s, off);
    s += __shfl_xor(s, 32);

    __shared__ float smem[kWavesPerBlock];
    __shared__ int   sIsLast;
    if (lane == 0) smem[wave] = s;
    __syncthreads();
    if (tid == 0) {
        const float blocksum = smem[0] + smem[1] + smem[2] + smem[3];
        // Release-publish this block's partial, then bump the counter.
        __hip_atomic_store(&partials[blockIdx.x], blocksum,
                           __ATOMIC_RELEASE, __HIP_MEMORY_SCOPE_AGENT);
        const int old = __hip_atomic_fetch_add(&g_done, 1,
                           __ATOMIC_ACQ_REL, __HIP_MEMORY_SCOPE_AGENT);
        sIsLast = (old == kBlocks - 1);
    }
    __syncthreads();

    if (sIsLast) {
        // Last block: all 2048 partials are published (acquire via fetch_add
        // + block barrier). Reduce in fixed index order -> deterministic,
        // identical tree to the old standalone reduce kernel.
        __threadfence();   // belt-and-suspenders cache acquire for teammates
        float acc = 0.0f;
        for (int i = tid; i < kBlocks; i += 256)
            acc += __hip_atomic_load(&partials[i],
                       __ATOMIC_RELAXED, __HIP_MEMORY_SCOPE_AGENT);
        #pragma unroll
        for (int off = 32; off > 0; off >>= 1)
            acc += __shfl_xor(acc, off);
        __shared__ float sm2[kWavesPerBlock];
        if (lane == 0) sm2[wave] = acc;
        __syncthreads();
        if (tid == 0) {
            out[0] = -(sm2[0] + sm2[1] + sm2[2] + sm2[3]) / (float)kB;
            // Self-reset for the next graph replay (kernel-boundary ordering
            // guarantees the next dispatch sees 0).
            __hip_atomic_store(&g_done, 0,
                               __ATOMIC_RELAXED, __HIP_MEMORY_SCOPE_AGENT);
        }
    }
}

extern "C" void kernel_launch(void* const* d_in, const int* in_sizes, int n_in,
                              void* d_out, int out_size, void* d_ws, size_t ws_size,
                              hipStream_t stream) {
    const int*   input_word   = (const int*)d_in[0];
    const int*   context_word = (const int*)d_in[1];
    const int*   noise_words  = (const int*)d_in[2];
    const float* W_in         = (const float*)d_in[3];
    const float* W_ctx        = (const float*)d_in[4];
    float*       out          = (float*)d_out;
    float*       partials     = (float*)d_ws;   // kBlocks floats (8 KiB)

    w2v_loss_fused<<<kBlocks, 256, 0, stream>>>(
        input_word, context_word, noise_words, W_in, W_ctx, partials, out);
}

// Round 5
// 188.425 us; speedup vs baseline: 1.3251x; 1.3251x over previous
//
#include <hip/hip_runtime.h>

// Problem constants (from reference)
constexpr int kB   = 16384;   // batch
constexpr int kNeg = 10;      // negatives per example
constexpr int kE   = 128;     // embedding dim
constexpr int kWavesPerBlock = 4;                 // 256 threads
constexpr int kExPerWave     = 2;                 // 32 lanes per example
constexpr int kBlocks = kB / (kWavesPerBlock * kExPerWave);   // 2048

// Module-scope completion counter (not in the re-poisoned workspace).
// Self-resets to 0 at the end of every dispatch -> graph-replay safe.
__device__ int g_done = 0;

__device__ __forceinline__ float log_sigmoid(float x) {
    // numerically stable: min(x,0) - log1p(exp(-|x|))
    return fminf(x, 0.0f) - log1pf(expf(-fabsf(x)));
}

__device__ __forceinline__ float dot4(float4 a, float4 b) {
    return a.x * b.x + a.y * b.y + a.z * b.z + a.w * b.w;
}

// R0-proven gather body + last-block-done reduction.
// Memory-ordering design (the R4 lesson): agent-scope ACQUIRE on gfx950
// compiles to buffer_inv, which invalidates the whole per-XCD L2 -- done
// per-block it destroys the cached embedding rows (40 us -> 152 us).
// Here: producers use sc1 (agent-coherent) RELAXED stores for partials
// (no dirty L2 line) + RELEASE-only fetch_add (waitcnt + wbl2 over zero
// dirty lines = ~free, NO buffer_inv). Only sc1 loads in the single last
// block; no acquire fence anywhere.
__global__ __launch_bounds__(256, 4) void w2v_loss_fused(
    const int*   __restrict__ input_word,
    const int*   __restrict__ context_word,
    const int*   __restrict__ noise_words,
    const float* __restrict__ W_in,
    const float* __restrict__ W_ctx,
    float*       __restrict__ partials,
    float*       __restrict__ out)
{
    const int tid  = threadIdx.x;
    const int wave = tid >> 6;
    const int lane = tid & 63;
    const int half = lane >> 5;               // which example of the wave
    const int l32  = lane & 31;               // lane within 32-lane group

    const int b = (blockIdx.x * kWavesPerBlock + wave) * kExPerWave + half;

    // Load all indices first (independent scalar loads).
    const int iw = input_word[b];
    const int cw = context_word[b];
    int nw[kNeg];
    #pragma unroll
    for (int k = 0; k < kNeg; ++k)
        nw[k] = noise_words[b * kNeg + k];

    // Issue all 12 row gathers back-to-back (each 1 float4/lane, 512B/row).
    const float4 c = ((const float4*)(W_in  + (size_t)iw * kE))[l32];
    const float4 x = ((const float4*)(W_ctx + (size_t)cw * kE))[l32];
    float4 nv[kNeg];
    #pragma unroll
    for (int k = 0; k < kNeg; ++k)
        nv[k] = ((const float4*)(W_ctx + (size_t)nw[k] * kE))[l32];

    float pos = dot4(c, x);
    float negp[kNeg];
    #pragma unroll
    for (int k = 0; k < kNeg; ++k)
        negp[k] = dot4(c, nv[k]);

    // 5-step butterfly within each 32-lane half (xor masks < 32 stay in-half).
    #pragma unroll
    for (int off = 16; off > 0; off >>= 1) {
        pos += __shfl_xor(pos, off);
        #pragma unroll
        for (int k = 0; k < kNeg; ++k)
            negp[k] += __shfl_xor(negp[k], off);
    }
    // Every lane now holds all 11 full dot products for its example.

    // Distribute the 11 log_sigmoid evaluations across lanes 0..10 of the half.
    float v = pos;                          // lane 0: positive score
    #pragma unroll
    for (int k = 0; k < kNeg; ++k)
        v = (l32 == k + 1) ? -negp[k] : v;  // lanes 1..10: negated neg scores
    float s = (l32 < 1 + kNeg) ? log_sigmoid(v) : 0.0f;

    // Sum the 11 terms within the half (5 steps), then across halves (1 step).
    #pragma unroll
    for (int off = 16; off > 0; off >>= 1)
        s += __shfl_xor(s, off);
    s += __shfl_xor(s, 32);

    __shared__ float smem[kWavesPerBlock];
    __shared__ int   sIsLast;
    if (lane == 0) smem[wave] = s;
    __syncthreads();
    if (tid == 0) {
        const float blocksum = smem[0] + smem[1] + smem[2] + smem[3];
        // sc1 agent-coherent store: lands at the coherence point directly,
        // leaves no dirty line in the (non-coherent) XCD L2.
        __hip_atomic_store(&partials[blockIdx.x], blocksum,
                           __ATOMIC_RELAXED, __HIP_MEMORY_SCOPE_AGENT);
        // RELEASE only: s_waitcnt orders the partials store before the
        // increment; no acquire -> no buffer_inv -> L2-cached embedding
        // rows of co-resident blocks survive.
        const int old = __hip_atomic_fetch_add(&g_done, 1,
                           __ATOMIC_RELEASE, __HIP_MEMORY_SCOPE_AGENT);
        sIsLast = (old == kBlocks - 1);
    }
    __syncthreads();

    if (sIsLast) {
        // All 2048 partials are at the coherence point (each producer's
        // release ordered its sc1 store before its increment). sc1 loads
        // read the coherence point -> no invalidate needed. Fixed index
        // order -> bit-identical to the standalone reduce kernel.
        float acc = 0.0f;
        for (int i = tid; i < kBlocks; i += 256)
            acc += __hip_atomic_load(&partials[i],
                       __ATOMIC_RELAXED, __HIP_MEMORY_SCOPE_AGENT);
        #pragma unroll
        for (int off = 32; off > 0; off >>= 1)
            acc += __shfl_xor(acc, off);
        __shared__ float sm2[kWavesPerBlock];
        if (lane == 0) sm2[wave] = acc;
        __syncthreads();
        if (tid == 0) {
            out[0] = -(sm2[0] + sm2[1] + sm2[2] + sm2[3]) / (float)kB;
            // Self-reset for the next graph replay (stream-serialized, so
            // no race with the next dispatch's first fetch_add).
            __hip_atomic_store(&g_done, 0,
                               __ATOMIC_RELAXED, __HIP_MEMORY_SCOPE_AGENT);
        }
    }
}

extern "C" void kernel_launch(void* const* d_in, const int* in_sizes, int n_in,
                              void* d_out, int out_size, void* d_ws, size_t ws_size,
                              hipStream_t stream) {
    const int*   input_word   = (const int*)d_in[0];
    const int*   context_word = (const int*)d_in[1];
    const int*   noise_words  = (const int*)d_in[2];
    const float* W_in         = (const float*)d_in[3];
    const float* W_ctx        = (const float*)d_in[4];
    float*       out          = (float*)d_out;
    float*       partials     = (float*)d_ws;   // kBlocks floats (8 KiB)

    w2v_loss_fused<<<kBlocks, 256, 0, stream>>>(
        input_word, context_word, noise_words, W_in, W_ctx, partials, out);
}

// Round 7
// 139.862 us; speedup vs baseline: 1.7853x; 1.3472x over previous
//
#include <hip/hip_runtime.h>

// Problem constants (from reference)
constexpr int kB   = 16384;   // batch
constexpr int kNeg = 10;      // negatives per example
constexpr int kE   = 128;     // embedding dim
constexpr int kWavesPerBlock = 4;                 // 256 threads
constexpr int kExPerWave     = 2;                 // 32 lanes per example
constexpr int kBlocks = kB / (kWavesPerBlock * kExPerWave);   // 2048

// Module-scope completion counter (not in the re-poisoned workspace).
// Self-resets to 0 at the end of every dispatch -> graph-replay safe.
__device__ int g_done = 0;

__device__ __forceinline__ float log_sigmoid(float x) {
    // numerically stable: min(x,0) - log1p(exp(-|x|))
    return fminf(x, 0.0f) - log1pf(expf(-fabsf(x)));
}

__device__ __forceinline__ float dot4(float4 a, float4 b) {
    return a.x * b.x + a.y * b.y + a.z * b.z + a.w * b.w;
}

// R0-proven gather body + last-block-done reduction.
//
// Memory-ordering ladder learned on this chip (R4 -> R5 -> now):
//   R4: per-block agent ACQ_REL  -> buffer_inv per block (L2 nuked): 152 us
//   R5: per-block agent RELEASE  -> buffer_wbl2 + full drain per block: 89 us
//   now: sc1 RELAXED store + one `s_waitcnt vmcnt(0)` + RELAXED fetch_add
//        -> ZERO cache-maintenance ops. The sc1 store writes through to the
//        coherence point (no dirty L2 line), so waiting for its completion
//        (vmcnt) is a complete release for it. Consumer reads partials with
//        sc1 relaxed loads (reads the coherence point; nothing to invalidate).
__global__ __launch_bounds__(256, 4) void w2v_loss_fused(
    const int*   __restrict__ input_word,
    const int*   __restrict__ context_word,
    const int*   __restrict__ noise_words,
    const float* __restrict__ W_in,
    const float* __restrict__ W_ctx,
    float*       __restrict__ partials,
    float*       __restrict__ out)
{
    const int tid  = threadIdx.x;
    const int wave = tid >> 6;
    const int lane = tid & 63;
    const int half = lane >> 5;               // which example of the wave
    const int l32  = lane & 31;               // lane within 32-lane group

    const int b = (blockIdx.x * kWavesPerBlock + wave) * kExPerWave + half;

    // Load all indices first (independent scalar loads).
    const int iw = input_word[b];
    const int cw = context_word[b];
    int nw[kNeg];
    #pragma unroll
    for (int k = 0; k < kNeg; ++k)
        nw[k] = noise_words[b * kNeg + k];

    // Issue all 12 row gathers back-to-back (each 1 float4/lane, 512B/row).
    const float4 c = ((const float4*)(W_in  + (size_t)iw * kE))[l32];
    const float4 x = ((const float4*)(W_ctx + (size_t)cw * kE))[l32];
    float4 nv[kNeg];
    #pragma unroll
    for (int k = 0; k < kNeg; ++k)
        nv[k] = ((const float4*)(W_ctx + (size_t)nw[k] * kE))[l32];

    float pos = dot4(c, x);
    float negp[kNeg];
    #pragma unroll
    for (int k = 0; k < kNeg; ++k)
        negp[k] = dot4(c, nv[k]);

    // 5-step butterfly within each 32-lane half (xor masks < 32 stay in-half).
    #pragma unroll
    for (int off = 16; off > 0; off >>= 1) {
        pos += __shfl_xor(pos, off);
        #pragma unroll
        for (int k = 0; k < kNeg; ++k)
            negp[k] += __shfl_xor(negp[k], off);
    }
    // Every lane now holds all 11 full dot products for its example.

    // Distribute the 11 log_sigmoid evaluations across lanes 0..10 of the half.
    float v = pos;                          // lane 0: positive score
    #pragma unroll
    for (int k = 0; k < kNeg; ++k)
        v = (l32 == k + 1) ? -negp[k] : v;  // lanes 1..10: negated neg scores
    float s = (l32 < 1 + kNeg) ? log_sigmoid(v) : 0.0f;

    // Sum the 11 terms within the half (5 steps), then across halves (1 step).
    #pragma unroll
    for (int off = 16; off > 0; off >>= 1)
        s += __shfl_xor(s, off);
    s += __shfl_xor(s, 32);

    __shared__ float smem[kWavesPerBlock];
    __shared__ int   sIsLast;
    if (lane == 0) smem[wave] = s;
    __syncthreads();
    if (tid == 0) {
        const float blocksum = smem[0] + smem[1] + smem[2] + smem[3];
        // sc1 agent-coherent relaxed store: writes through to the coherence
        // point, leaves no dirty line in the (non-coherent) XCD L2.
        __hip_atomic_store(&partials[blockIdx.x], blocksum,
                           __ATOMIC_RELAXED, __HIP_MEMORY_SCOPE_AGENT);
        // Hand-rolled release sufficient for an sc1 store: wait for its
        // completion only. No buffer_wbl2, no buffer_inv. The "memory"
        // clobber keeps the following atomic from hoisting above the wait.
        asm volatile("s_waitcnt vmcnt(0)" ::: "memory");
        const int old = __hip_atomic_fetch_add(&g_done, 1,
                           __ATOMIC_RELAXED, __HIP_MEMORY_SCOPE_AGENT);
        sIsLast = (old == kBlocks - 1);
    }
    __syncthreads();

    if (sIsLast) {
        // Every producer's partial reached the coherence point before its
        // increment, and we saw all kBlocks increments -> all partials
        // visible to sc1 loads. Fixed index order -> bit-identical to the
        // standalone reduce kernel.
        float acc = 0.0f;
        for (int i = tid; i < kBlocks; i += 256)
            acc += __hip_atomic_load(&partials[i],
                       __ATOMIC_RELAXED, __HIP_MEMORY_SCOPE_AGENT);
        #pragma unroll
        for (int off = 32; off > 0; off >>= 1)
            acc += __shfl_xor(acc, off);
        __shared__ float sm2[kWavesPerBlock];
        if (lane == 0) sm2[wave] = acc;
        __syncthreads();
        if (tid == 0) {
            out[0] = -(sm2[0] + sm2[1] + sm2[2] + sm2[3]) / (float)kB;
            // Self-reset for the next graph replay (stream-serialized, so
            // no race with the next dispatch's first fetch_add).
            __hip_atomic_store(&g_done, 0,
                               __ATOMIC_RELAXED, __HIP_MEMORY_SCOPE_AGENT);
        }
    }
}

extern "C" void kernel_launch(void* const* d_in, const int* in_sizes, int n_in,
                              void* d_out, int out_size, void* d_ws, size_t ws_size,
                              hipStream_t stream) {
    const int*   input_word   = (const int*)d_in[0];
    const int*   context_word = (const int*)d_in[1];
    const int*   noise_words  = (const int*)d_in[2];
    const float* W_in         = (const float*)d_in[3];
    const float* W_ctx        = (const float*)d_in[4];
    float*       out          = (float*)d_out;
    float*       partials     = (float*)d_ws;   // kBlocks floats (8 KiB)

    w2v_loss_fused<<<kBlocks, 256, 0, stream>>>(
        input_word, context_word, noise_words, W_in, W_ctx, partials, out);
}

// Round 8
// 124.591 us; speedup vs baseline: 2.0041x; 1.1226x over previous
//
#include <hip/hip_runtime.h>

// Problem constants (from reference)
constexpr int kB   = 16384;   // batch
constexpr int kNeg = 10;      // negatives per example
constexpr int kE   = 128;     // embedding dim
constexpr int kWavesPerBlock = 4;                 // 256 threads
constexpr int kExPerWave     = 2;                 // 32 lanes per example
constexpr int kBlocks = kB / (kWavesPerBlock * kExPerWave);   // 2048

__device__ __forceinline__ float log_sigmoid(float x) {
    // numerically stable: min(x,0) - log1p(exp(-|x|))
    return fminf(x, 0.0f) - log1pf(expf(-fabsf(x)));
}

__device__ __forceinline__ float dot4(float4 a, float4 b) {
    return a.x * b.x + a.y * b.y + a.z * b.z + a.w * b.w;
}

// 32 lanes per example: one float4 per lane covers the E=128 row exactly.
// All 12 row gathers per lane are independent -> max memory-level parallelism.
// Session evidence (R0-R7): this body runs ~25 us (47 MB random 512B gather
// at ~1.9 TB/s) and is insensitive to 2x occupancy (R1), access-pattern
// inversion (R2), and kernel fusion (R3/R4/R5/R7 all regressed). The
// two-kernel graph beats every fused variant: the last-block atomic funnel
// costs +15 us vs the ~5 us reduce-node total.
__global__ __launch_bounds__(256, 4) void w2v_loss_kernel(
    const int*   __restrict__ input_word,
    const int*   __restrict__ context_word,
    const int*   __restrict__ noise_words,
    const float* __restrict__ W_in,
    const float* __restrict__ W_ctx,
    float*       __restrict__ partials)
{
    const int lane = threadIdx.x & 63;
    const int wave = threadIdx.x >> 6;
    const int half = lane >> 5;               // which example of the wave
    const int l32  = lane & 31;               // lane within 32-lane group

    const int b = (blockIdx.x * kWavesPerBlock + wave) * kExPerWave + half;

    // Load all indices first (independent scalar loads).
    const int iw = input_word[b];
    const int cw = context_word[b];
    int nw[kNeg];
    #pragma unroll
    for (int k = 0; k < kNeg; ++k)
        nw[k] = noise_words[b * kNeg + k];

    // Issue all 12 row gathers back-to-back (each 1 float4/lane, coalesced 512B/row).
    const float4 c = ((const float4*)(W_in  + (size_t)iw * kE))[l32];
    const float4 x = ((const float4*)(W_ctx + (size_t)cw * kE))[l32];
    float4 nv[kNeg];
    #pragma unroll
    for (int k = 0; k < kNeg; ++k)
        nv[k] = ((const float4*)(W_ctx + (size_t)nw[k] * kE))[l32];

    float pos = dot4(c, x);
    float negp[kNeg];
    #pragma unroll
    for (int k = 0; k < kNeg; ++k)
        negp[k] = dot4(c, nv[k]);

    // 5-step butterfly within each 32-lane half (xor masks < 32 stay in-half).
    #pragma unroll
    for (int off = 16; off > 0; off >>= 1) {
        pos += __shfl_xor(pos, off);
        #pragma unroll
        for (int k = 0; k < kNeg; ++k)
            negp[k] += __shfl_xor(negp[k], off);
    }
    // Every lane now holds all 11 full dot products for its example.

    // Distribute the 11 log_sigmoid evaluations across lanes 0..10 of the half.
    float v = pos;                          // lane 0: positive score
    #pragma unroll
    for (int k = 0; k < kNeg; ++k)
        v = (l32 == k + 1) ? -negp[k] : v;  // lanes 1..10: negated neg scores
    float s = (l32 < 1 + kNeg) ? log_sigmoid(v) : 0.0f;

    // Sum the 11 terms within the half (5 steps), then across halves (1 step).
    #pragma unroll
    for (int off = 16; off > 0; off >>= 1)
        s += __shfl_xor(s, off);
    s += __shfl_xor(s, 32);

    __shared__ float smem[kWavesPerBlock];
    if (lane == 0) smem[wave] = s;
    __syncthreads();
    if (threadIdx.x == 0)
        partials[blockIdx.x] = smem[0] + smem[1] + smem[2] + smem[3];
}

__global__ __launch_bounds__(256) void w2v_reduce_kernel(
    const float* __restrict__ partials,
    float*       __restrict__ out)
{
    float acc = 0.0f;
    for (int i = threadIdx.x; i < kBlocks; i += 256)
        acc += partials[i];

    #pragma unroll
    for (int off = 32; off > 0; off >>= 1)
        acc += __shfl_xor(acc, off);

    __shared__ float smem[4];
    const int lane = threadIdx.x & 63;
    const int wave = threadIdx.x >> 6;
    if (lane == 0) smem[wave] = acc;
    __syncthreads();
    if (threadIdx.x == 0) {
        const float total = smem[0] + smem[1] + smem[2] + smem[3];
        out[0] = -total / (float)kB;
    }
}

extern "C" void kernel_launch(void* const* d_in, const int* in_sizes, int n_in,
                              void* d_out, int out_size, void* d_ws, size_t ws_size,
                              hipStream_t stream) {
    const int*   input_word   = (const int*)d_in[0];
    const int*   context_word = (const int*)d_in[1];
    const int*   noise_words  = (const int*)d_in[2];
    const float* W_in         = (const float*)d_in[3];
    const float* W_ctx        = (const float*)d_in[4];
    float*       out          = (float*)d_out;
    float*       partials     = (float*)d_ws;   // kBlocks floats (8 KiB)

    w2v_loss_kernel<<<kBlocks, 256, 0, stream>>>(
        input_word, context_word, noise_words, W_in, W_ctx, partials);
    w2v_reduce_kernel<<<1, 256, 0, stream>>>(partials, out);
}